// Round 3
// baseline (237.949 us; speedup 1.0000x reference)
//
#include <hip/hip_runtime.h>
#include <math.h>

// minGRU bidirectional scan, fused single pass, ONE-SHOT per row.
// x: [8, 512, 8192] fp32. out: [8, 256, 8192] fp32.
//   a_t = sigmoid(-gate_t); b_t = sigmoid(gate_t)*g(h_t); H_t = a_t*H_{t-1} + b_t
//   g(h) = h>=0 ? h+1 : exp(h)
// One block (512 threads x 16 elems) processes one full row of 8192:
//   - every thread's 8 float4 loads issue at block start (max MLP, no tile loop)
//   - per-thread local scan from zero state -> (ov0[], pp[])
//   - wave-level shfl scan of (pa,pb) pair composition
//   - ONE barrier; cross-wave fold of 8 LDS partials (unrolled, predicated)
//   - ov[j] = ov0[j] + st * pp[j] (in place), nontemporal float4 stores
// __launch_bounds__(512, 4): VGPR cap 128 (no spill risk for ~90 live floats),
// 8 waves/block within a 4-waves/EU budget -> 2 blocks/CU co-resident so one
// block's load burst overlaps the other block's compute/store tail.

#define SEQ_L 8192
#define NTHREADS 512
#define PER_THREAD 16

typedef float f4 __attribute__((ext_vector_type(4)));

__global__ __launch_bounds__(NTHREADS, 4) void mingru_scan_kernel(
    const float* __restrict__ x, float* __restrict__ out) {
    const int blk = blockIdx.x;          // 0..2047
    const int dir = blk >> 10;           // 0 = forward, 1 = backward
    const int s   = blk & 1023;
    const int b   = s >> 7;              // batch 0..7
    const int c   = s & 127;             // channel 0..127

    const int tid  = threadIdx.x;        // 0..511
    const int lane = tid & 63;
    const int wave = tid >> 6;           // 0..7

    const float* __restrict__ hrow = x + (size_t)((b * 512) + (dir * 256) + c) * SEQ_L;
    const float* __restrict__ grow = hrow + (size_t)128 * SEQ_L;
    float* __restrict__ orow = out + (size_t)((b * 256) + (dir * 128) + c) * SEQ_L;

    __shared__ float sA[8];
    __shared__ float sB[8];

    // ---- one-shot loads: entire row's worth for this thread, issued together ----
    const int base = tid * PER_THREAD;
    const int idx  = dir ? (SEQ_L - base - PER_THREAD) : base;

    const f4 h0 = __builtin_nontemporal_load((const f4*)(hrow + idx));
    const f4 h1 = __builtin_nontemporal_load((const f4*)(hrow + idx + 4));
    const f4 h2 = __builtin_nontemporal_load((const f4*)(hrow + idx + 8));
    const f4 h3 = __builtin_nontemporal_load((const f4*)(hrow + idx + 12));
    const f4 g0 = __builtin_nontemporal_load((const f4*)(grow + idx));
    const f4 g1 = __builtin_nontemporal_load((const f4*)(grow + idx + 4));
    const f4 g2 = __builtin_nontemporal_load((const f4*)(grow + idx + 8));
    const f4 g3 = __builtin_nontemporal_load((const f4*)(grow + idx + 12));

    // ---- unpack into scan order (register permutation, block-uniform branch) ----
    float hv[PER_THREAD], gv[PER_THREAD];
    if (dir == 0) {
        hv[ 0]=h0.x; hv[ 1]=h0.y; hv[ 2]=h0.z; hv[ 3]=h0.w;
        hv[ 4]=h1.x; hv[ 5]=h1.y; hv[ 6]=h1.z; hv[ 7]=h1.w;
        hv[ 8]=h2.x; hv[ 9]=h2.y; hv[10]=h2.z; hv[11]=h2.w;
        hv[12]=h3.x; hv[13]=h3.y; hv[14]=h3.z; hv[15]=h3.w;
        gv[ 0]=g0.x; gv[ 1]=g0.y; gv[ 2]=g0.z; gv[ 3]=g0.w;
        gv[ 4]=g1.x; gv[ 5]=g1.y; gv[ 6]=g1.z; gv[ 7]=g1.w;
        gv[ 8]=g2.x; gv[ 9]=g2.y; gv[10]=g2.z; gv[11]=g2.w;
        gv[12]=g3.x; gv[13]=g3.y; gv[14]=g3.z; gv[15]=g3.w;
    } else {
        hv[ 0]=h3.w; hv[ 1]=h3.z; hv[ 2]=h3.y; hv[ 3]=h3.x;
        hv[ 4]=h2.w; hv[ 5]=h2.z; hv[ 6]=h2.y; hv[ 7]=h2.x;
        hv[ 8]=h1.w; hv[ 9]=h1.z; hv[10]=h1.y; hv[11]=h1.x;
        hv[12]=h0.w; hv[13]=h0.z; hv[14]=h0.y; hv[15]=h0.x;
        gv[ 0]=g3.w; gv[ 1]=g3.z; gv[ 2]=g3.y; gv[ 3]=g3.x;
        gv[ 4]=g2.w; gv[ 5]=g2.z; gv[ 6]=g2.y; gv[ 7]=g2.x;
        gv[ 8]=g1.w; gv[ 9]=g1.z; gv[10]=g1.y; gv[11]=g1.x;
        gv[12]=g0.w; gv[13]=g0.z; gv[14]=g0.y; gv[15]=g0.x;
    }

    // ---- coefficients + local scan from zero state; keep (ov0, pp) ----
    float pp[PER_THREAD], ov0[PER_THREAD];
    float ca = 1.0f, cb = 0.0f;
#pragma unroll
    for (int j = 0; j < PER_THREAD; ++j) {
        const float gt = gv[j];
        const float e  = __expf(-fabsf(gt));
        const float r  = 1.0f / (1.0f + e);
        const float sn = e * r;                   // sigmoid(-|gt|)
        const float z  = (gt >= 0.0f) ? r  : sn;  // sigmoid(gt)
        const float a  = (gt >= 0.0f) ? sn : r;   // sigmoid(-gt)
        const float hh = hv[j];
        const float gf = (hh >= 0.0f) ? (hh + 1.0f) : __expf(hh);
        const float bb = z * gf;
        cb = a * cb + bb;
        ca = a * ca;
        ov0[j] = cb;
        pp[j]  = ca;
    }

    // ---- inclusive wave scan of (pa,pb) pair composition ----
    float pa = ca, pb = cb;
#pragma unroll
    for (int d = 1; d < 64; d <<= 1) {
        const float oa = __shfl_up(pa, d);
        const float ob = __shfl_up(pb, d);
        if (lane >= d) {
            pb = pa * ob + pb;   // compose with earlier segment
            pa = pa * oa;
        }
    }

    if (lane == 63) { sA[wave] = pa; sB[wave] = pb; }
    __syncthreads();   // the ONLY barrier

    // ---- state entering this wave: fold partials of waves < wave.
    // Unrolled so the 7 LDS reads are independent (one lgkmcnt batch),
    // predicated FMA chain (wave-uniform, no divergence). wave 7 needs w<=6.
    float st = 0.0f;
#pragma unroll
    for (int w = 0; w < 7; ++w) {
        const float aw = sA[w];
        const float bw = sB[w];
        if (w < wave) st = aw * st + bw;
    }

    // ---- state entering this thread ----
    float ea = __shfl_up(pa, 1);
    float eb = __shfl_up(pb, 1);
    if (lane == 0) { ea = 1.0f; eb = 0.0f; }
    st = ea * st + eb;

    // ---- outputs via correction (independent fmas, in place) ----
#pragma unroll
    for (int j = 0; j < PER_THREAD; ++j) ov0[j] = ov0[j] + st * pp[j];

    // ---- store (reversed for backward); streaming data -> nontemporal ----
    if (dir == 0) {
        f4 o0; o0.x = ov0[ 0]; o0.y = ov0[ 1]; o0.z = ov0[ 2]; o0.w = ov0[ 3];
        f4 o1; o1.x = ov0[ 4]; o1.y = ov0[ 5]; o1.z = ov0[ 6]; o1.w = ov0[ 7];
        f4 o2; o2.x = ov0[ 8]; o2.y = ov0[ 9]; o2.z = ov0[10]; o2.w = ov0[11];
        f4 o3; o3.x = ov0[12]; o3.y = ov0[13]; o3.z = ov0[14]; o3.w = ov0[15];
        __builtin_nontemporal_store(o0, (f4*)(orow + base));
        __builtin_nontemporal_store(o1, (f4*)(orow + base + 4));
        __builtin_nontemporal_store(o2, (f4*)(orow + base + 8));
        __builtin_nontemporal_store(o3, (f4*)(orow + base + 12));
    } else {
        // scan element j sits at global position idx + (15 - j)
        f4 o0; o0.x = ov0[15]; o0.y = ov0[14]; o0.z = ov0[13]; o0.w = ov0[12];
        f4 o1; o1.x = ov0[11]; o1.y = ov0[10]; o1.z = ov0[ 9]; o1.w = ov0[ 8];
        f4 o2; o2.x = ov0[ 7]; o2.y = ov0[ 6]; o2.z = ov0[ 5]; o2.w = ov0[ 4];
        f4 o3; o3.x = ov0[ 3]; o3.y = ov0[ 2]; o3.z = ov0[ 1]; o3.w = ov0[ 0];
        __builtin_nontemporal_store(o0, (f4*)(orow + idx));
        __builtin_nontemporal_store(o1, (f4*)(orow + idx + 4));
        __builtin_nontemporal_store(o2, (f4*)(orow + idx + 8));
        __builtin_nontemporal_store(o3, (f4*)(orow + idx + 12));
    }
}

extern "C" void kernel_launch(void* const* d_in, const int* in_sizes, int n_in,
                              void* d_out, int out_size, void* d_ws, size_t ws_size,
                              hipStream_t stream) {
    const float* x = (const float*)d_in[0];
    float* out = (float*)d_out;
    mingru_scan_kernel<<<2048, NTHREADS, 0, stream>>>(x, out);
}

// Round 4
// 213.815 us; speedup vs baseline: 1.1129x; 1.1129x over previous
//
#include <hip/hip_runtime.h>
#include <math.h>

// minGRU bidirectional scan, fused single pass, ONE-SHOT per row.
// x: [8, 512, 8192] fp32. out: [8, 256, 8192] fp32.
//   a_t = sigmoid(-gate_t); b_t = sigmoid(gate_t)*g(h_t); H_t = a_t*H_{t-1} + b_t
//   g(h) = h>=0 ? h+1 : exp(h)
// One block (1024 threads x 8 elems) processes one full row of 8192:
//   - every thread's 4 float4 loads issue at block start (max MLP, no tile loop)
//   - per-thread local scan from zero state -> (ov0[], pp[])
//   - wave-level shfl scan of (pa,pb) pair composition
//   - ONE barrier; cross-wave fold of 16 LDS partials (unrolled, predicated)
//   - ov[j] = ov0[j] + st * pp[j], nontemporal float4 stores
//
// Config notes (measured):
//   1024x8 @ __launch_bounds__(1024,8): 64-VGPR cap -> 32 waves/CU. 201.6 us.
//   512x16 @ (512,4): compiler free to ~120 VGPR -> 16 waves/CU, TLP-starved,
//     237.9 us. REVERTED. TLP is what hides the one-shot burst latency.
//   Loads are PLAIN (cached): lane stride is 32B, each dwordx4 pair uses
//     complementary halves of each 128B line -> second half must hit L2;
//     nt (evict-first) risks HBM re-fetch. Stores stay NT (write-once).

#define SEQ_L 8192
#define NTHREADS 1024
#define PER_THREAD 8

typedef float f4 __attribute__((ext_vector_type(4)));

__global__ __launch_bounds__(NTHREADS, 8) void mingru_scan_kernel(
    const float* __restrict__ x, float* __restrict__ out) {
    const int blk = blockIdx.x;          // 0..2047
    const int dir = blk >> 10;           // 0 = forward, 1 = backward
    const int s   = blk & 1023;
    const int b   = s >> 7;              // batch 0..7
    const int c   = s & 127;             // channel 0..127

    const int tid  = threadIdx.x;        // 0..1023
    const int lane = tid & 63;
    const int wave = tid >> 6;           // 0..15

    const float* __restrict__ hrow = x + (size_t)((b * 512) + (dir * 256) + c) * SEQ_L;
    const float* __restrict__ grow = hrow + (size_t)128 * SEQ_L;
    float* __restrict__ orow = out + (size_t)((b * 256) + (dir * 128) + c) * SEQ_L;

    __shared__ float sA[16];
    __shared__ float sB[16];

    // ---- one-shot loads: entire row's worth for this thread, issued together ----
    const int base = tid * PER_THREAD;
    const int idx  = dir ? (SEQ_L - base - PER_THREAD) : base;

    const f4 h0 = *(const f4*)(hrow + idx);
    const f4 h1 = *(const f4*)(hrow + idx + 4);
    const f4 g0 = *(const f4*)(grow + idx);
    const f4 g1 = *(const f4*)(grow + idx + 4);

    // ---- unpack into scan order (register permutation, block-uniform branch) ----
    float hv[PER_THREAD], gv[PER_THREAD];
    if (dir == 0) {
        hv[0]=h0.x; hv[1]=h0.y; hv[2]=h0.z; hv[3]=h0.w;
        hv[4]=h1.x; hv[5]=h1.y; hv[6]=h1.z; hv[7]=h1.w;
        gv[0]=g0.x; gv[1]=g0.y; gv[2]=g0.z; gv[3]=g0.w;
        gv[4]=g1.x; gv[5]=g1.y; gv[6]=g1.z; gv[7]=g1.w;
    } else {
        hv[0]=h1.w; hv[1]=h1.z; hv[2]=h1.y; hv[3]=h1.x;
        hv[4]=h0.w; hv[5]=h0.z; hv[6]=h0.y; hv[7]=h0.x;
        gv[0]=g1.w; gv[1]=g1.z; gv[2]=g1.y; gv[3]=g1.x;
        gv[4]=g0.w; gv[5]=g0.z; gv[6]=g0.y; gv[7]=g0.x;
    }

    // ---- coefficients + local scan from zero state; keep (ov0, pp) ----
    float pp[PER_THREAD], ov0[PER_THREAD];
    float ca = 1.0f, cb = 0.0f;
#pragma unroll
    for (int j = 0; j < PER_THREAD; ++j) {
        const float gt = gv[j];
        const float e  = __expf(-fabsf(gt));
        const float r  = 1.0f / (1.0f + e);
        const float sn = e * r;                   // sigmoid(-|gt|)
        const float z  = (gt >= 0.0f) ? r  : sn;  // sigmoid(gt)
        const float a  = (gt >= 0.0f) ? sn : r;   // sigmoid(-gt)
        const float hh = hv[j];
        const float gf = (hh >= 0.0f) ? (hh + 1.0f) : __expf(hh);
        const float bb = z * gf;
        cb = a * cb + bb;
        ca = a * ca;
        ov0[j] = cb;
        pp[j]  = ca;
    }

    // ---- inclusive wave scan of (pa,pb) pair composition ----
    float pa = ca, pb = cb;
#pragma unroll
    for (int d = 1; d < 64; d <<= 1) {
        const float oa = __shfl_up(pa, d);
        const float ob = __shfl_up(pb, d);
        if (lane >= d) {
            pb = pa * ob + pb;   // compose with earlier segment
            pa = pa * oa;
        }
    }

    if (lane == 63) { sA[wave] = pa; sB[wave] = pb; }
    __syncthreads();   // the ONLY barrier

    // ---- state entering this wave: fold partials of waves < wave.
    // Unrolled so the 15 LDS reads are independent (one lgkmcnt batch),
    // predicated FMA chain (wave-uniform, no divergence). wave 15 needs w<=14.
    float st = 0.0f;
#pragma unroll
    for (int w = 0; w < 15; ++w) {
        const float aw = sA[w];
        const float bw = sB[w];
        if (w < wave) st = aw * st + bw;
    }

    // ---- state entering this thread ----
    float ea = __shfl_up(pa, 1);
    float eb = __shfl_up(pb, 1);
    if (lane == 0) { ea = 1.0f; eb = 0.0f; }
    st = ea * st + eb;

    // ---- outputs via correction (independent fmas, no serial chain) ----
    float ov[PER_THREAD];
#pragma unroll
    for (int j = 0; j < PER_THREAD; ++j) ov[j] = ov0[j] + st * pp[j];

    // ---- store (reversed for backward); streaming data -> nontemporal ----
    if (dir == 0) {
        f4 o0; o0.x = ov[0]; o0.y = ov[1]; o0.z = ov[2]; o0.w = ov[3];
        f4 o1; o1.x = ov[4]; o1.y = ov[5]; o1.z = ov[6]; o1.w = ov[7];
        __builtin_nontemporal_store(o0, (f4*)(orow + base));
        __builtin_nontemporal_store(o1, (f4*)(orow + base + 4));
    } else {
        f4 o0; o0.x = ov[7]; o0.y = ov[6]; o0.z = ov[5]; o0.w = ov[4];
        f4 o1; o1.x = ov[3]; o1.y = ov[2]; o1.z = ov[1]; o1.w = ov[0];
        __builtin_nontemporal_store(o0, (f4*)(orow + idx));
        __builtin_nontemporal_store(o1, (f4*)(orow + idx + 4));
    }
}

extern "C" void kernel_launch(void* const* d_in, const int* in_sizes, int n_in,
                              void* d_out, int out_size, void* d_ws, size_t ws_size,
                              hipStream_t stream) {
    const float* x = (const float*)d_in[0];
    float* out = (float*)d_out;
    mingru_scan_kernel<<<2048, NTHREADS, 0, stream>>>(x, out);
}

// Round 5
// 200.725 us; speedup vs baseline: 1.1854x; 1.0652x over previous
//
#include <hip/hip_runtime.h>
#include <math.h>

// minGRU bidirectional scan, fused single pass, ONE-SHOT per row.
// x: [8, 512, 8192] fp32. out: [8, 256, 8192] fp32.
//   a_t = sigmoid(-gate_t); b_t = sigmoid(gate_t)*g(h_t); H_t = a_t*H_{t-1} + b_t
//   g(h) = h>=0 ? h+1 : exp(h)
// One block (1024 threads x 8 elems) processes one full row of 8192:
//   - every thread's 4 float4 loads issue at block start (max MLP, no tile loop)
//   - per-thread local scan from zero state -> (ov0[], pp[])
//   - wave-level shfl scan of (pa,pb) pair composition
//   - ONE barrier; cross-wave fold of 16 LDS partials (unrolled, predicated)
//   - ov[j] = ov0[j] + st * pp[j], nontemporal float4 stores
//
// Config notes (ALL MEASURED — do not re-try):
//   * 1024x8 @ (1024,8), NT loads+stores: 201.65 us  <- THIS KERNEL (best)
//   * 512x16 @ (512,4): ~120 VGPR -> 16 waves/CU, TLP-starved: 237.9 us
//   * 1024x8 with PLAIN (cached) loads, NT stores: 213.8 us — NT loads help
//     (streaming evict-first; no reuse, cached lines just pollute L2)
//   * 4-tile software-pipelined loop (256x8x4): ~209.6 us
// Remaining gap vs composite floor (~195 us = 161 us harness fills + 32 us
// traffic floor + partial compute overlap) is ~3%: structural (compute phase
// of each block generation only partially overlaps other blocks' memory).

#define SEQ_L 8192
#define NTHREADS 1024
#define PER_THREAD 8

typedef float f4 __attribute__((ext_vector_type(4)));

__global__ __launch_bounds__(NTHREADS, 8) void mingru_scan_kernel(
    const float* __restrict__ x, float* __restrict__ out) {
    const int blk = blockIdx.x;          // 0..2047
    const int dir = blk >> 10;           // 0 = forward, 1 = backward
    const int s   = blk & 1023;
    const int b   = s >> 7;              // batch 0..7
    const int c   = s & 127;             // channel 0..127

    const int tid  = threadIdx.x;        // 0..1023
    const int lane = tid & 63;
    const int wave = tid >> 6;           // 0..15

    const float* __restrict__ hrow = x + (size_t)((b * 512) + (dir * 256) + c) * SEQ_L;
    const float* __restrict__ grow = hrow + (size_t)128 * SEQ_L;
    float* __restrict__ orow = out + (size_t)((b * 256) + (dir * 128) + c) * SEQ_L;

    __shared__ float sA[16];
    __shared__ float sB[16];

    // ---- one-shot loads: entire row's worth for this thread, issued together ----
    const int base = tid * PER_THREAD;
    const int idx  = dir ? (SEQ_L - base - PER_THREAD) : base;

    const f4 h0 = __builtin_nontemporal_load((const f4*)(hrow + idx));
    const f4 h1 = __builtin_nontemporal_load((const f4*)(hrow + idx + 4));
    const f4 g0 = __builtin_nontemporal_load((const f4*)(grow + idx));
    const f4 g1 = __builtin_nontemporal_load((const f4*)(grow + idx + 4));

    // ---- unpack into scan order (register permutation, block-uniform branch) ----
    float hv[PER_THREAD], gv[PER_THREAD];
    if (dir == 0) {
        hv[0]=h0.x; hv[1]=h0.y; hv[2]=h0.z; hv[3]=h0.w;
        hv[4]=h1.x; hv[5]=h1.y; hv[6]=h1.z; hv[7]=h1.w;
        gv[0]=g0.x; gv[1]=g0.y; gv[2]=g0.z; gv[3]=g0.w;
        gv[4]=g1.x; gv[5]=g1.y; gv[6]=g1.z; gv[7]=g1.w;
    } else {
        hv[0]=h1.w; hv[1]=h1.z; hv[2]=h1.y; hv[3]=h1.x;
        hv[4]=h0.w; hv[5]=h0.z; hv[6]=h0.y; hv[7]=h0.x;
        gv[0]=g1.w; gv[1]=g1.z; gv[2]=g1.y; gv[3]=g1.x;
        gv[4]=g0.w; gv[5]=g0.z; gv[6]=g0.y; gv[7]=g0.x;
    }

    // ---- coefficients + local scan from zero state; keep (ov0, pp) ----
    float pp[PER_THREAD], ov0[PER_THREAD];
    float ca = 1.0f, cb = 0.0f;
#pragma unroll
    for (int j = 0; j < PER_THREAD; ++j) {
        const float gt = gv[j];
        const float e  = __expf(-fabsf(gt));
        const float r  = 1.0f / (1.0f + e);
        const float sn = e * r;                   // sigmoid(-|gt|)
        const float z  = (gt >= 0.0f) ? r  : sn;  // sigmoid(gt)
        const float a  = (gt >= 0.0f) ? sn : r;   // sigmoid(-gt)
        const float hh = hv[j];
        const float gf = (hh >= 0.0f) ? (hh + 1.0f) : __expf(hh);
        const float bb = z * gf;
        cb = a * cb + bb;
        ca = a * ca;
        ov0[j] = cb;
        pp[j]  = ca;
    }

    // ---- inclusive wave scan of (pa,pb) pair composition ----
    float pa = ca, pb = cb;
#pragma unroll
    for (int d = 1; d < 64; d <<= 1) {
        const float oa = __shfl_up(pa, d);
        const float ob = __shfl_up(pb, d);
        if (lane >= d) {
            pb = pa * ob + pb;   // compose with earlier segment
            pa = pa * oa;
        }
    }

    if (lane == 63) { sA[wave] = pa; sB[wave] = pb; }
    __syncthreads();   // the ONLY barrier

    // ---- state entering this wave: fold partials of waves < wave.
    // Unrolled so the 15 LDS reads are independent (one lgkmcnt batch),
    // predicated FMA chain (wave-uniform, no divergence). wave 15 needs w<=14.
    float st = 0.0f;
#pragma unroll
    for (int w = 0; w < 15; ++w) {
        const float aw = sA[w];
        const float bw = sB[w];
        if (w < wave) st = aw * st + bw;
    }

    // ---- state entering this thread ----
    float ea = __shfl_up(pa, 1);
    float eb = __shfl_up(pb, 1);
    if (lane == 0) { ea = 1.0f; eb = 0.0f; }
    st = ea * st + eb;

    // ---- outputs via correction (independent fmas, no serial chain) ----
    float ov[PER_THREAD];
#pragma unroll
    for (int j = 0; j < PER_THREAD; ++j) ov[j] = ov0[j] + st * pp[j];

    // ---- store (reversed for backward); streaming data -> nontemporal ----
    if (dir == 0) {
        f4 o0; o0.x = ov[0]; o0.y = ov[1]; o0.z = ov[2]; o0.w = ov[3];
        f4 o1; o1.x = ov[4]; o1.y = ov[5]; o1.z = ov[6]; o1.w = ov[7];
        __builtin_nontemporal_store(o0, (f4*)(orow + base));
        __builtin_nontemporal_store(o1, (f4*)(orow + base + 4));
    } else {
        f4 o0; o0.x = ov[7]; o0.y = ov[6]; o0.z = ov[5]; o0.w = ov[4];
        f4 o1; o1.x = ov[3]; o1.y = ov[2]; o1.z = ov[1]; o1.w = ov[0];
        __builtin_nontemporal_store(o0, (f4*)(orow + idx));
        __builtin_nontemporal_store(o1, (f4*)(orow + idx + 4));
    }
}

extern "C" void kernel_launch(void* const* d_in, const int* in_sizes, int n_in,
                              void* d_out, int out_size, void* d_ws, size_t ws_size,
                              hipStream_t stream) {
    const float* x = (const float*)d_in[0];
    float* out = (float*)d_out;
    mingru_scan_kernel<<<2048, NTHREADS, 0, stream>>>(x, out);
}